// Round 2
// baseline (184.409 us; speedup 1.0000x reference)
//
#include <hip/hip_runtime.h>
#include <math.h>

// QueryDynamicAttention: B=16, N=1024, D=768, MU=768, R=16, DR=48
// out = (x * sigmoid(channel_att)) * sigmoid(spatial)
//   channel_att = W2 @ (relu(W1@avg+b1) + relu(W1@max+b1)) + 2*b2   (linear merge)
//   spatial[b,n] = dot(x_gated[b,n,:], Ws[b,:]) + bs[b]
// Hypernet GEMM (mu @ Wg*, M=16, K=768, N=74.5K, 226 MB) is HBM-bound.
// This round: K-split x4 + float2 lanes for concurrency (was 12% occupancy).

#define B_  16
#define N_  1024
#define D_  768
#define MU_ 768

// ---------------------------------------------------------------------------
// k_pool: avg/max pooling partials over N (32 chunks of 32 tokens) + mu transpose
__global__ __launch_bounds__(192) void k_pool(
    const float* __restrict__ x, const float* __restrict__ mu,
    float* __restrict__ mu_t, float* __restrict__ psum, float* __restrict__ pmax)
{
    int blk = blockIdx.x;
    if (blk == 512) {  // mu transpose: mu_t[m][b] = mu[b][m]
        for (int e = threadIdx.x; e < MU_ * B_; e += 192) {
            int m = e >> 4, b = e & 15;
            mu_t[e] = mu[b * MU_ + m];
        }
        return;
    }
    int b = blk >> 5, c = blk & 31;
    int d4 = threadIdx.x << 2;
    const float* xp = x + ((size_t)(b * N_ + c * 32)) * D_ + d4;
    float s0 = 0.f, s1 = 0.f, s2 = 0.f, s3 = 0.f;
    float m0 = -3.4e38f, m1 = -3.4e38f, m2 = -3.4e38f, m3 = -3.4e38f;
    for (int n = 0; n < 32; ++n) {
        float4 v = *(const float4*)(xp + (size_t)n * D_);
        s0 += v.x; s1 += v.y; s2 += v.z; s3 += v.w;
        m0 = fmaxf(m0, v.x); m1 = fmaxf(m1, v.y);
        m2 = fmaxf(m2, v.z); m3 = fmaxf(m3, v.w);
    }
    size_t o = ((size_t)(c * B_ + b)) * D_ + d4;
    float4 sv = { s0, s1, s2, s3 }; *(float4*)(psum + o) = sv;
    float4 mv = { m0, m1, m2, m3 }; *(float4*)(pmax + o) = mv;
}

// ---------------------------------------------------------------------------
// k_hyper: per-sample weights from mu. Big path: Wg1/Wg2 (113 MB each),
// K-chunked (NCHUNK), 2 cols/lane (float2), 1 wave/block -> partials.
// Small path (Wgs/Bg1/Bg2/Bgs) also chunked, merged into same launch.
template<int NCHUNK>
__global__ __launch_bounds__(64) void k_hyper(
    const float* __restrict__ Wg1, const float* __restrict__ bg1,
    const float* __restrict__ Wg2, const float* __restrict__ bg2,
    const float* __restrict__ Wgs, const float* __restrict__ bgs,
    const float* __restrict__ Bg1, const float* __restrict__ bb1,
    const float* __restrict__ Bg2, const float* __restrict__ bb2,
    const float* __restrict__ Bgs, const float* __restrict__ bbs,
    const float* __restrict__ mu_t,
    float* __restrict__ w1p, float* __restrict__ w2p,
    float* __restrict__ wswp, float* __restrict__ b1p,
    float* __restrict__ b2p, float* __restrict__ bsp)
{
    constexpr int CH = MU_ / NCHUNK;
    const int NBIG = 2 * 288 * NCHUNK;
    int t = blockIdx.x, ln = threadIdx.x;

    if (t < NBIG) {
        int mi = t / (288 * NCHUNK);
        int r  = t % (288 * NCHUNK);
        int c = r / 288, tile = r % 288;
        const float* mat  = mi ? Wg2 : Wg1;
        const float* bias = mi ? bg2 : bg1;
        float* outp = (mi ? w2p : w1p) + (size_t)c * 589824;   // 16*36864
        int j = tile * 128 + (ln << 1);
        const float* p  = mat + (size_t)(c * CH) * 36864 + j;
        const float* mr = mu_t + c * CH * 16;

        float a0[16], a1[16];
        #pragma unroll
        for (int b = 0; b < 16; ++b) { a0[b] = 0.f; a1[b] = 0.f; }

        #pragma unroll 8
        for (int m = 0; m < CH; ++m) {
            float2 w = *(const float2*)p; p += 36864;
            #pragma unroll
            for (int b = 0; b < 16; ++b) {
                a0[b] = fmaf(mr[b], w.x, a0[b]);
                a1[b] = fmaf(mr[b], w.y, a1[b]);
            }
            mr += 16;
        }
        float2 bv = { 0.f, 0.f };
        if (c == 0) bv = *(const float2*)(bias + j);
        #pragma unroll
        for (int b = 0; b < 16; ++b) {
            float2 o = { a0[b] + bv.x, a1[b] + bv.y };
            *(float2*)(outp + (size_t)b * 36864 + j) = o;
        }
        return;
    }

    // small path: 14 tile-groups x NCHUNK
    int s  = t - NBIG;
    int sm = s / NCHUNK, c = s % NCHUNK;
    const float* mat; const float* bias; float* outp; int ncols; int tile = 0;
    if (sm < 6)       { mat = Wgs; bias = bgs; outp = wswp + c * 12288; ncols = 768; tile = sm; }
    else if (sm < 12) { mat = Bg2; bias = bb2; outp = b2p  + c * 12288; ncols = 768; tile = sm - 6; }
    else if (sm == 12){ mat = Bg1; bias = bb1; outp = b1p  + c * 768;   ncols = 48; }
    else              { mat = Bgs; bias = bbs; outp = bsp  + c * 16;    ncols = 1; }

    int j0 = tile * 128 + ln, j1 = j0 + 64;
    bool v0 = j0 < ncols, v1 = j1 < ncols;
    const float* p0 = mat + (size_t)(c * CH) * ncols + (v0 ? j0 : 0);
    const float* p1 = mat + (size_t)(c * CH) * ncols + (v1 ? j1 : 0);
    const float* mr = mu_t + c * CH * 16;

    float a0[16], a1[16];
    #pragma unroll
    for (int b = 0; b < 16; ++b) { a0[b] = 0.f; a1[b] = 0.f; }

    #pragma unroll 4
    for (int m = 0; m < CH; ++m) {
        float w0 = *p0, w1 = *p1;
        p0 += ncols; p1 += ncols;
        #pragma unroll
        for (int b = 0; b < 16; ++b) {
            a0[b] = fmaf(mr[b], w0, a0[b]);
            a1[b] = fmaf(mr[b], w1, a1[b]);
        }
        mr += 16;
    }
    float bv0 = (c == 0 && v0) ? bias[j0] : 0.f;
    float bv1 = (c == 0 && v1) ? bias[j1] : 0.f;
    #pragma unroll
    for (int b = 0; b < 16; ++b) {
        if (v0) outp[(size_t)b * ncols + j0] = a0[b] + bv0;
        if (v1) outp[(size_t)b * ncols + j1] = a1[b] + bv1;
    }
}

// ---------------------------------------------------------------------------
// k_c1a: finish pooling; partial dots pa/pm per (b, chunk). grid 16*nc x 256.
__global__ __launch_bounds__(256) void k_c1a(
    const float* __restrict__ psum, const float* __restrict__ pmax,
    const float* __restrict__ w1p,
    float* __restrict__ pap, float* __restrict__ pmp, int nc)
{
    __shared__ float avgL[768], maxL[768];
    int b = blockIdx.x / nc, c = blockIdx.x % nc;
    int tid = threadIdx.x;
    for (int d = tid; d < D_; d += 256) {
        float s = 0.f, mx = -3.4e38f;
        for (int pc = 0; pc < 32; ++pc) {
            size_t idx = ((size_t)(pc * B_ + b)) * D_ + d;
            s += psum[idx];
            mx = fmaxf(mx, pmax[idx]);
        }
        avgL[d] = s * (1.f / 1024.f);
        maxL[d] = mx;
    }
    __syncthreads();
    int wv = tid >> 6, ln = tid & 63;
    const float* wbase = w1p + (size_t)c * 589824 + (size_t)b * 36864;
    for (int o = wv; o < 48; o += 4) {
        const float* row = wbase + o * 768;
        float pa = 0.f, pm = 0.f;
        for (int i = ln; i < 768; i += 64) {
            float w = row[i];
            pa += w * avgL[i];
            pm += w * maxL[i];
        }
        #pragma unroll
        for (int k = 32; k; k >>= 1) {
            pa += __shfl_xor(pa, k, 64);
            pm += __shfl_xor(pm, k, 64);
        }
        if (ln == 0) {
            pap[c * 768 + b * 48 + o] = pa;
            pmp[c * 768 + b * 48 + o] = pm;
        }
    }
}

// ---------------------------------------------------------------------------
// k_c2: g = relu(pa+b1)+relu(pm+b1); att = W2@g + 2*b2; cg = sigmoid.
// Also finalizes Ws and bs (chunk sums). grid 96 x 128.
__global__ __launch_bounds__(128) void k_c2(
    const float* __restrict__ w2p, const float* __restrict__ pap,
    const float* __restrict__ pmp, const float* __restrict__ b1p,
    const float* __restrict__ b2p, const float* __restrict__ wswp,
    const float* __restrict__ bsp,
    float* __restrict__ cg, float* __restrict__ wsw, float* __restrict__ bs,
    int nc)
{
    __shared__ float gL[48];
    int b = blockIdx.x / 6, ch = blockIdx.x % 6, tid = threadIdx.x;
    if (tid < 48) {
        float pa = 0.f, pm = 0.f, bb = 0.f;
        for (int c = 0; c < nc; ++c) {
            pa += pap[c * 768 + b * 48 + tid];
            pm += pmp[c * 768 + b * 48 + tid];
            bb += b1p[c * 768 + b * 48 + tid];
        }
        gL[tid] = fmaxf(pa + bb, 0.f) + fmaxf(pm + bb, 0.f);
    }
    __syncthreads();
    int d = (ch << 7) + tid;
    float att = 0.f;
    for (int c = 0; c < nc; ++c) {
        const float* row = w2p + (size_t)c * 589824 + (size_t)b * 36864 + d * 48;
        float a = 0.f;
        #pragma unroll
        for (int o = 0; o < 48; o += 4) {
            float4 w4 = *(const float4*)(row + o);
            a += w4.x * gL[o] + w4.y * gL[o + 1] + w4.z * gL[o + 2] + w4.w * gL[o + 3];
        }
        att += a;
    }
    float b2v = 0.f;
    for (int c = 0; c < nc; ++c) b2v += b2p[c * 12288 + b * 768 + d];
    att += 2.f * b2v;
    cg[b * D_ + d] = 1.f / (1.f + expf(-att));
    float wv = 0.f;
    for (int c = 0; c < nc; ++c) wv += wswp[c * 12288 + b * 768 + d];
    wsw[b * D_ + d] = wv;
    if (ch == 0 && tid == 0) {
        float sv = 0.f;
        for (int c = 0; c < nc; ++c) sv += bsp[c * 16 + b];
        bs[b] = sv;
    }
}

// ---------------------------------------------------------------------------
// k_final: one wave per token: xg = x*cg; s = dot(xg, Ws)+bs; out = xg*sigmoid(s).
__global__ __launch_bounds__(256) void k_final(
    const float* __restrict__ x, const float* __restrict__ cg,
    const float* __restrict__ wsw, const float* __restrict__ bs,
    float* __restrict__ out)
{
    int wv = threadIdx.x >> 6, ln = threadIdx.x & 63;
    int tok = (blockIdx.x << 2) + wv;
    int b = tok >> 10;
    const float* xp = x + (size_t)tok * D_;
    const float* cp = cg + b * D_;
    const float* wp = wsw + b * D_;
    float xg[12];
    float part = 0.f;
    #pragma unroll
    for (int q = 0; q < 3; ++q) {
        int d = (q << 8) + (ln << 2);
        float4 xv = *(const float4*)(xp + d);
        float4 cv = *(const float4*)(cp + d);
        float4 w4 = *(const float4*)(wp + d);
        float g0 = xv.x * cv.x, g1 = xv.y * cv.y;
        float g2 = xv.z * cv.z, g3 = xv.w * cv.w;
        part += g0 * w4.x + g1 * w4.y + g2 * w4.z + g3 * w4.w;
        xg[q * 4 + 0] = g0; xg[q * 4 + 1] = g1;
        xg[q * 4 + 2] = g2; xg[q * 4 + 3] = g3;
    }
    #pragma unroll
    for (int k = 32; k; k >>= 1) part += __shfl_xor(part, k, 64);
    float s = part + bs[b];
    float sig = 1.f / (1.f + expf(-s));
    #pragma unroll
    for (int q = 0; q < 3; ++q) {
        int d = (q << 8) + (ln << 2);
        float4 o4 = { xg[q * 4 + 0] * sig, xg[q * 4 + 1] * sig,
                      xg[q * 4 + 2] * sig, xg[q * 4 + 3] * sig };
        *(float4*)(out + (size_t)tok * D_ + d) = o4;
    }
}

// ---------------------------------------------------------------------------
extern "C" void kernel_launch(void* const* d_in, const int* in_sizes, int n_in,
                              void* d_out, int out_size, void* d_ws, size_t ws_size,
                              hipStream_t stream)
{
    const float* x   = (const float*)d_in[0];
    const float* mu  = (const float*)d_in[1];
    const float* Wg1 = (const float*)d_in[2];
    const float* bg1 = (const float*)d_in[3];
    const float* Bg1 = (const float*)d_in[4];
    const float* bb1 = (const float*)d_in[5];
    const float* Wg2 = (const float*)d_in[6];
    const float* bg2 = (const float*)d_in[7];
    const float* Bg2 = (const float*)d_in[8];
    const float* bb2 = (const float*)d_in[9];
    const float* Wgs = (const float*)d_in[10];
    const float* bgs = (const float*)d_in[11];
    const float* Bgs = (const float*)d_in[12];
    const float* bbs = (const float*)d_in[13];
    float* base = (float*)d_ws;
    float* out  = (float*)d_out;

    // ws budget: fixed head 798720 floats, per-chunk 1206544, fixed tail 24592
    auto need_bytes = [](int nc) -> size_t {
        return ((size_t)823312 + (size_t)nc * 1206544) * 4;
    };
    int nc = (ws_size >= need_bytes(4)) ? 4 : (ws_size >= need_bytes(2)) ? 2 : 1;

    float* mu_t = base;
    float* psum = mu_t + 12288;
    float* pmax = psum + 393216;
    float* w1p  = pmax + 393216;
    float* w2p  = w1p  + (size_t)nc * 589824;
    float* wswp = w2p  + (size_t)nc * 589824;
    float* b1p  = wswp + (size_t)nc * 12288;
    float* b2p  = b1p  + (size_t)nc * 768;
    float* bsp  = b2p  + (size_t)nc * 12288;
    float* pap  = bsp  + (size_t)nc * 16;
    float* pmp  = pap  + (size_t)nc * 768;
    float* wsw  = pmp  + (size_t)nc * 768;
    float* bs   = wsw  + 12288;
    float* cg   = bs   + 16;

    hipLaunchKernelGGL(k_pool, dim3(513), dim3(192), 0, stream, x, mu, mu_t, psum, pmax);

    int nblk = 2 * 288 * nc + 14 * nc;
    if (nc == 4)
        hipLaunchKernelGGL(k_hyper<4>, dim3(nblk), dim3(64), 0, stream,
                           Wg1, bg1, Wg2, bg2, Wgs, bgs, Bg1, bb1, Bg2, bb2, Bgs, bbs,
                           mu_t, w1p, w2p, wswp, b1p, b2p, bsp);
    else if (nc == 2)
        hipLaunchKernelGGL(k_hyper<2>, dim3(nblk), dim3(64), 0, stream,
                           Wg1, bg1, Wg2, bg2, Wgs, bgs, Bg1, bb1, Bg2, bb2, Bgs, bbs,
                           mu_t, w1p, w2p, wswp, b1p, b2p, bsp);
    else
        hipLaunchKernelGGL(k_hyper<1>, dim3(nblk), dim3(64), 0, stream,
                           Wg1, bg1, Wg2, bg2, Wgs, bgs, Bg1, bb1, Bg2, bb2, Bgs, bbs,
                           mu_t, w1p, w2p, wswp, b1p, b2p, bsp);

    hipLaunchKernelGGL(k_c1a, dim3(16 * nc), dim3(256), 0, stream,
                       psum, pmax, w1p, pap, pmp, nc);
    hipLaunchKernelGGL(k_c2, dim3(96), dim3(128), 0, stream,
                       w2p, pap, pmp, b1p, b2p, wswp, bsp, cg, wsw, bs, nc);
    hipLaunchKernelGGL(k_final, dim3(4096), dim3(256), 0, stream, x, cg, wsw, bs, out);
}

// Round 4
// 168.994 us; speedup vs baseline: 1.0912x; 1.0912x over previous
//
#include <hip/hip_runtime.h>
#include <math.h>

// QueryDynamicAttention: B=16, N=1024, D=768, MU=768, R=16, DR=48
// out = (x * sigmoid(channel_att)) * sigmoid(spatial)
//   channel_att = W2 @ (relu(W1@avg+b1) + relu(W1@max+b1)) + 2*b2
//   spatial[b,n] = dot(x_gated[b,n,:], Ws[b,:]) + bs[b]
// Hypernet GEMM (mu @ Wg*, 226 MB streamed) is HBM-bound: the whole game is
// memory-level parallelism. Round 4: fix k_hyper reduce column mapping
// (even/odd interleave bug) + coalesced float2 epilogue.

#define B_  16
#define N_  1024
#define D_  768
#define MU_ 768

// ---------------------------------------------------------------------------
// k_pool: avg/max pooling partials over N (32 chunks of 32 tokens) + mu transpose
__global__ __launch_bounds__(192) void k_pool(
    const float* __restrict__ x, const float* __restrict__ mu,
    float* __restrict__ mu_t, float* __restrict__ psum, float* __restrict__ pmax)
{
    int blk = blockIdx.x;
    if (blk == 512) {  // mu_t[m][b] = mu[b][m]
        for (int e = threadIdx.x; e < MU_ * B_; e += 192) {
            int m = e >> 4, b = e & 15;
            mu_t[e] = mu[b * MU_ + m];
        }
        return;
    }
    int b = blk >> 5, c = blk & 31;
    int d4 = threadIdx.x << 2;
    const float* xp = x + ((size_t)(b * N_ + c * 32)) * D_ + d4;
    float s0 = 0.f, s1 = 0.f, s2 = 0.f, s3 = 0.f;
    float m0 = -3.4e38f, m1 = -3.4e38f, m2 = -3.4e38f, m3 = -3.4e38f;
    for (int n = 0; n < 32; ++n) {
        float4 v = *(const float4*)(xp + (size_t)n * D_);
        s0 += v.x; s1 += v.y; s2 += v.z; s3 += v.w;
        m0 = fmaxf(m0, v.x); m1 = fmaxf(m1, v.y);
        m2 = fmaxf(m2, v.z); m3 = fmaxf(m3, v.w);
    }
    size_t o = ((size_t)(c * B_ + b)) * D_ + d4;
    float4 sv = { s0, s1, s2, s3 }; *(float4*)(psum + o) = sv;
    float4 mv = { m0, m1, m2, m3 }; *(float4*)(pmax + o) = mv;
}

// ---------------------------------------------------------------------------
// k_hyper: out[b][j] = sum_m mu[b][m]*M[m][j] + bias[j] for Wg1/Wg2/Wgs/Bg2.
// 588 blocks x 512 thr (8 waves). Block covers 128 cols (float2/lane) of one
// matrix; wave w handles K rows [96w, 96w+96); LDS reduce at the end.
// Lane ln owns columns base+2*ln (a0) and base+2*ln+1 (a1).
__global__ __launch_bounds__(512, 4) void k_hyper(
    const float* __restrict__ Wg1, const float* __restrict__ bg1,
    const float* __restrict__ Wg2, const float* __restrict__ bg2,
    const float* __restrict__ Wgs, const float* __restrict__ bgs,
    const float* __restrict__ Bg2, const float* __restrict__ bb2,
    const float* __restrict__ mu_t,
    float* __restrict__ w1o, float* __restrict__ w2o,
    float* __restrict__ wso, float* __restrict__ b2o)
{
    __shared__ float red[8][32][64];   // [wave][k][lane] = 64 KB
    int t = blockIdx.x;
    int w = threadIdx.x >> 6, ln = threadIdx.x & 63;

    const float* mat; const float* bias; float* outp; int ncols; int base;
    if (t < 288)      { mat = Wg1; bias = bg1; outp = w1o; ncols = 36864; base = t << 7; }
    else if (t < 576) { mat = Wg2; bias = bg2; outp = w2o; ncols = 36864; base = (t - 288) << 7; }
    else if (t < 582) { mat = Wgs; bias = bgs; outp = wso; ncols = 768;   base = (t - 576) << 7; }
    else              { mat = Bg2; bias = bb2; outp = b2o; ncols = 768;   base = (t - 582) << 7; }

    int m0 = w * 96;
    int j = base + (ln << 1);                       // exact tiling: always valid
    const float* p = mat + (size_t)m0 * ncols + j;
    const float* mup = mu_t + m0 * 16;

    float a0[16], a1[16];
    #pragma unroll
    for (int b = 0; b < 16; ++b) { a0[b] = 0.f; a1[b] = 0.f; }

    constexpr int DP = 8;                           // rotation depth
    float2 f[DP];
    #pragma unroll
    for (int d = 0; d < DP; ++d) { f[d] = *(const float2*)p; p += ncols; }

    for (int it = 0; it < 96 / DP; ++it) {
        #pragma unroll
        for (int d = 0; d < DP; ++d) {
            float2 wv = f[d];
            if (it < 96 / DP - 1) { f[d] = *(const float2*)p; p += ncols; }
            #pragma unroll
            for (int b = 0; b < 16; ++b) {
                a0[b] = fmaf(mup[b], wv.x, a0[b]);
                a1[b] = fmaf(mup[b], wv.y, a1[b]);
            }
            mup += 16;
        }
    }

    // stage: red[w][b][ln] = a0[b] (col base+2ln), red[w][16+b][ln] = a1[b] (col base+2ln+1)
    #pragma unroll
    for (int b = 0; b < 16; ++b) {
        red[w][b][ln]      = a0[b];
        red[w][16 + b][ln] = a1[b];
    }
    __syncthreads();

    // reduce: thread (w, l2) handles b = w and b = w+8; writes float2 at col base+2*l2
    int l2 = ln;
    #pragma unroll
    for (int half = 0; half < 2; ++half) {
        int b = w + (half << 3);
        float s0 = 0.f, s1 = 0.f;
        #pragma unroll
        for (int ww = 0; ww < 8; ++ww) {
            s0 += red[ww][b][l2];
            s1 += red[ww][16 + b][l2];
        }
        int col = base + (l2 << 1);
        float2 o = { s0 + bias[col], s1 + bias[col + 1] };
        *(float2*)(outp + (size_t)b * ncols + col) = o;
    }
}

// ---------------------------------------------------------------------------
// k_red: finalize avg/max pooling (96 blocks); tile 0 also computes
// bs[b] = dot(mu[b], Bgs) + bbs.
__global__ __launch_bounds__(128) void k_red(
    const float* __restrict__ psum, const float* __restrict__ pmax,
    const float* __restrict__ mu, const float* __restrict__ Bgs,
    const float* __restrict__ bbs,
    float* __restrict__ avgb, float* __restrict__ maxb, float* __restrict__ bs)
{
    int b = blockIdx.x / 6, tile = blockIdx.x % 6, tid = threadIdx.x;
    int d = tile * 128 + tid;
    float s = 0.f, mx = -3.4e38f;
    for (int c = 0; c < 32; ++c) {
        size_t idx = ((size_t)(c * B_ + b)) * D_ + d;
        s += psum[idx];
        mx = fmaxf(mx, pmax[idx]);
    }
    avgb[b * D_ + d] = s * (1.f / 1024.f);
    maxb[b * D_ + d] = mx;

    if (tile == 0) {
        __shared__ float sb[128];
        float p = 0.f;
        for (int m = tid; m < MU_; m += 128) p += mu[b * MU_ + m] * Bgs[m];
        sb[tid] = p;
        __syncthreads();
        if (tid < 64) {
            float v = sb[tid] + sb[tid + 64];
            #pragma unroll
            for (int k = 32; k; k >>= 1) v += __shfl_xor(v, k, 64);
            if (tid == 0) bs[b] = v + bbs[0];
        }
    }
}

// ---------------------------------------------------------------------------
// k_c1: g[b][o] = relu(W1[b,o]@avg + b1) + relu(W1[b,o]@max + b1),
// b1 = dot(mu[b], Bg1[:,o]) + bb1[o] folded in. grid 768 x 64 (1 wave).
__global__ __launch_bounds__(64) void k_c1(
    const float* __restrict__ w1, const float* __restrict__ avgb,
    const float* __restrict__ maxb, const float* __restrict__ mu,
    const float* __restrict__ Bg1, const float* __restrict__ bb1,
    float* __restrict__ g)
{
    int b = blockIdx.x / 48, o = blockIdx.x % 48, ln = threadIdx.x;
    const float* row = w1 + (size_t)b * 36864 + o * 768;
    const float* av  = avgb + b * D_;
    const float* mxp = maxb + b * D_;
    const float* mub = mu + b * MU_;
    float pa = 0.f, pm = 0.f, pb = 0.f;
    #pragma unroll
    for (int i = 0; i < 12; ++i) {
        int idx = ln + (i << 6);
        float wv = row[idx];
        pa += wv * av[idx];
        pm += wv * mxp[idx];
        pb += Bg1[(size_t)idx * 48 + o] * mub[idx];
    }
    #pragma unroll
    for (int k = 32; k; k >>= 1) {
        pa += __shfl_xor(pa, k, 64);
        pm += __shfl_xor(pm, k, 64);
        pb += __shfl_xor(pb, k, 64);
    }
    if (ln == 0) {
        float bb = pb + bb1[o];
        g[b * 48 + o] = fmaxf(pa + bb, 0.f) + fmaxf(pm + bb, 0.f);
    }
}

// ---------------------------------------------------------------------------
// k_c2: att = W2[b,d,:]@g[b] + 2*b2[b,d]; cg = sigmoid(att). grid 192 x 64.
__global__ __launch_bounds__(64) void k_c2(
    const float* __restrict__ w2, const float* __restrict__ b2w,
    const float* __restrict__ g, float* __restrict__ cg)
{
    __shared__ float gL[48];
    int b = blockIdx.x / 12, tile = blockIdx.x % 12, ln = threadIdx.x;
    if (ln < 48) gL[ln] = g[b * 48 + ln];
    __syncthreads();
    int d = (tile << 6) + ln;
    const float* row = w2 + (size_t)b * 36864 + d * 48;
    float att = 0.f;
    #pragma unroll
    for (int o = 0; o < 48; o += 4) {
        float4 w4 = *(const float4*)(row + o);
        att += w4.x * gL[o] + w4.y * gL[o + 1] + w4.z * gL[o + 2] + w4.w * gL[o + 3];
    }
    att += 2.f * b2w[b * D_ + d];
    cg[b * D_ + d] = 1.f / (1.f + expf(-att));
}

// ---------------------------------------------------------------------------
// k_final: one wave per token: xg = x*cg; s = dot(xg, Ws)+bs; out = xg*sigmoid(s).
__global__ __launch_bounds__(256) void k_final(
    const float* __restrict__ x, const float* __restrict__ cg,
    const float* __restrict__ wsw, const float* __restrict__ bs,
    float* __restrict__ out)
{
    int wv = threadIdx.x >> 6, ln = threadIdx.x & 63;
    int tok = (blockIdx.x << 2) + wv;
    int b = tok >> 10;
    const float* xp = x + (size_t)tok * D_;
    const float* cp = cg + b * D_;
    const float* wp = wsw + b * D_;
    float xg[12];
    float part = 0.f;
    #pragma unroll
    for (int q = 0; q < 3; ++q) {
        int d = (q << 8) + (ln << 2);
        float4 xv = *(const float4*)(xp + d);
        float4 cv = *(const float4*)(cp + d);
        float4 w4 = *(const float4*)(wp + d);
        float g0 = xv.x * cv.x, g1 = xv.y * cv.y;
        float g2 = xv.z * cv.z, g3 = xv.w * cv.w;
        part += g0 * w4.x + g1 * w4.y + g2 * w4.z + g3 * w4.w;
        xg[q * 4 + 0] = g0; xg[q * 4 + 1] = g1;
        xg[q * 4 + 2] = g2; xg[q * 4 + 3] = g3;
    }
    #pragma unroll
    for (int k = 32; k; k >>= 1) part += __shfl_xor(part, k, 64);
    float s = part + bs[b];
    float sig = 1.f / (1.f + expf(-s));
    #pragma unroll
    for (int q = 0; q < 3; ++q) {
        int d = (q << 8) + (ln << 2);
        float4 o4 = { xg[q * 4 + 0] * sig, xg[q * 4 + 1] * sig,
                      xg[q * 4 + 2] * sig, xg[q * 4 + 3] * sig };
        *(float4*)(out + (size_t)tok * D_ + d) = o4;
    }
}

// ---------------------------------------------------------------------------
extern "C" void kernel_launch(void* const* d_in, const int* in_sizes, int n_in,
                              void* d_out, int out_size, void* d_ws, size_t ws_size,
                              hipStream_t stream)
{
    const float* x   = (const float*)d_in[0];
    const float* mu  = (const float*)d_in[1];
    const float* Wg1 = (const float*)d_in[2];
    const float* bg1 = (const float*)d_in[3];
    const float* Bg1 = (const float*)d_in[4];
    const float* bb1 = (const float*)d_in[5];
    const float* Wg2 = (const float*)d_in[6];
    const float* bg2 = (const float*)d_in[7];
    const float* Bg2 = (const float*)d_in[8];
    const float* bb2 = (const float*)d_in[9];
    const float* Wgs = (const float*)d_in[10];
    const float* bgs = (const float*)d_in[11];
    const float* Bgs = (const float*)d_in[12];
    const float* bbs = (const float*)d_in[13];
    float* base = (float*)d_ws;
    float* out  = (float*)d_out;

    float* mu_t = base;                  // 12288
    float* psum = mu_t + 12288;          // 393216
    float* pmax = psum + 393216;         // 393216
    float* w1   = pmax + 393216;         // 589824
    float* w2   = w1   + 589824;         // 589824
    float* wsw  = w2   + 589824;         // 12288
    float* b2   = wsw  + 12288;          // 12288
    float* avgb = b2   + 12288;          // 12288
    float* maxb = avgb + 12288;          // 12288
    float* g    = maxb + 12288;          // 768
    float* bs   = g    + 768;            // 16
    float* cg   = bs   + 16;             // 12288

    hipLaunchKernelGGL(k_pool,  dim3(513), dim3(192), 0, stream, x, mu, mu_t, psum, pmax);
    hipLaunchKernelGGL(k_hyper, dim3(588), dim3(512), 0, stream,
                       Wg1, bg1, Wg2, bg2, Wgs, bgs, Bg2, bb2,
                       mu_t, w1, w2, wsw, b2);
    hipLaunchKernelGGL(k_red,   dim3(96),  dim3(128), 0, stream,
                       psum, pmax, mu, Bgs, bbs, avgb, maxb, bs);
    hipLaunchKernelGGL(k_c1,    dim3(768), dim3(64),  0, stream,
                       w1, avgb, maxb, mu, Bg1, bb1, g);
    hipLaunchKernelGGL(k_c2,    dim3(192), dim3(64),  0, stream, w2, b2, g, cg);
    hipLaunchKernelGGL(k_final, dim3(4096), dim3(256), 0, stream, x, cg, wsw, bs, out);
}

// Round 5
// 106.248 us; speedup vs baseline: 1.7356x; 1.5906x over previous
//
#include <hip/hip_runtime.h>
#include <math.h>

// QueryDynamicAttention: B=16, N=1024, D=768, MU=768, R=16, DR=48
// out = (x * sigmoid(channel_att)) * sigmoid(spatial)
//   channel_att = W2 @ (relu(W1@avg+b1) + relu(W1@max+b1)) + 2*b2
//   spatial[b,n] = dot(x_gated[b,n,:], Ws[b,:]) + bs[b]
// Hypernet GEMM (mu @ Wg*, 226 MB streamed) is HBM-bound. Round 5:
// kill the two serial latency chains in k_hyper —
//   (a) mu via LDS broadcast (was per-row s_load on the critical path),
//   (b) unconditional peeled prefetch rotation (was depth-1: 810 cyc/row).

#define B_  16
#define N_  1024
#define D_  768
#define MU_ 768

// ---------------------------------------------------------------------------
// k_pool: avg/max pooling partials over N (32 chunks of 32 tokens) + mu transpose
__global__ __launch_bounds__(192) void k_pool(
    const float* __restrict__ x, const float* __restrict__ mu,
    float* __restrict__ mu_t, float* __restrict__ psum, float* __restrict__ pmax)
{
    int blk = blockIdx.x;
    if (blk == 512) {  // mu_t[m][b] = mu[b][m]
        for (int e = threadIdx.x; e < MU_ * B_; e += 192) {
            int m = e >> 4, b = e & 15;
            mu_t[e] = mu[b * MU_ + m];
        }
        return;
    }
    int b = blk >> 5, c = blk & 31;
    int d4 = threadIdx.x << 2;
    const float* xp = x + ((size_t)(b * N_ + c * 32)) * D_ + d4;
    float s0 = 0.f, s1 = 0.f, s2 = 0.f, s3 = 0.f;
    float m0 = -3.4e38f, m1 = -3.4e38f, m2 = -3.4e38f, m3 = -3.4e38f;
    for (int n = 0; n < 32; ++n) {
        float4 v = *(const float4*)(xp + (size_t)n * D_);
        s0 += v.x; s1 += v.y; s2 += v.z; s3 += v.w;
        m0 = fmaxf(m0, v.x); m1 = fmaxf(m1, v.y);
        m2 = fmaxf(m2, v.z); m3 = fmaxf(m3, v.w);
    }
    size_t o = ((size_t)(c * B_ + b)) * D_ + d4;
    float4 sv = { s0, s1, s2, s3 }; *(float4*)(psum + o) = sv;
    float4 mv = { m0, m1, m2, m3 }; *(float4*)(pmax + o) = mv;
}

// ---------------------------------------------------------------------------
// k_hyper: out[b][j] = sum_m mu[b][m]*M[m][j] + bias[j] for Wg1/Wg2/Wgs/Bg2.
// 588 blocks x 512 thr (8 waves). Block covers 128 cols (float2/lane);
// wave w handles K rows [96w, 96w+96). mu staged in LDS (broadcast reads);
// W streamed with depth-8 unconditional rotation; 4-pass LDS reduce.
// Static LDS = 48 KB (muL) + 16 KB (red2) = 64 KB -> 2 blocks/CU.

#define FMA4(U, K0) \
    a0[K0+0] = fmaf(U.x, wv.x, a0[K0+0]); a1[K0+0] = fmaf(U.x, wv.y, a1[K0+0]); \
    a0[K0+1] = fmaf(U.y, wv.x, a0[K0+1]); a1[K0+1] = fmaf(U.y, wv.y, a1[K0+1]); \
    a0[K0+2] = fmaf(U.z, wv.x, a0[K0+2]); a1[K0+2] = fmaf(U.z, wv.y, a1[K0+2]); \
    a0[K0+3] = fmaf(U.w, wv.x, a0[K0+3]); a1[K0+3] = fmaf(U.w, wv.y, a1[K0+3]);

__global__ __launch_bounds__(512, 4) void k_hyper(
    const float* __restrict__ Wg1, const float* __restrict__ bg1,
    const float* __restrict__ Wg2, const float* __restrict__ bg2,
    const float* __restrict__ Wgs, const float* __restrict__ bgs,
    const float* __restrict__ Bg2, const float* __restrict__ bb2,
    const float* __restrict__ mu_t,
    float* __restrict__ w1o, float* __restrict__ w2o,
    float* __restrict__ wso, float* __restrict__ b2o)
{
    __shared__ float muL[12288];        // 48 KB: mu_t [768][16]
    __shared__ float red2[8][8][64];    // 16 KB reduce buffer (4 passes)
    int t = blockIdx.x, tid = threadIdx.x;
    int w = tid >> 6, ln = tid & 63;

    const float* mat; const float* bias; float* outp; int ncols; int base;
    if (t < 288)      { mat = Wg1; bias = bg1; outp = w1o; ncols = 36864; base = t << 7; }
    else if (t < 576) { mat = Wg2; bias = bg2; outp = w2o; ncols = 36864; base = (t - 288) << 7; }
    else if (t < 582) { mat = Wgs; bias = bgs; outp = wso; ncols = 768;   base = (t - 576) << 7; }
    else              { mat = Bg2; bias = bb2; outp = b2o; ncols = 768;   base = (t - 582) << 7; }

    // stage mu into LDS (coalesced float4)
    {
        const float4* src = (const float4*)mu_t;
        float4* dst = (float4*)muL;
        #pragma unroll
        for (int i = 0; i < 6; ++i) dst[tid + i * 512] = src[tid + i * 512];
    }
    __syncthreads();

    int m0 = w * 96;
    int j = base + (ln << 1);                       // exact tiling: always valid
    const float* p = mat + (size_t)m0 * ncols + j;
    const float* mup = muL + (m0 << 4);

    float a0[16], a1[16];
    #pragma unroll
    for (int b = 0; b < 16; ++b) { a0[b] = 0.f; a1[b] = 0.f; }

    float2 f[8];
    #pragma unroll
    for (int d = 0; d < 8; ++d) { f[d] = *(const float2*)p; p += ncols; }

    for (int it = 0; it < 11; ++it) {               // steady state: loads unconditional
        #pragma unroll
        for (int d = 0; d < 8; ++d) {
            float2 wv = f[d];
            f[d] = *(const float2*)p; p += ncols;
            float4 u0 = *(const float4*)(mup);
            float4 u1 = *(const float4*)(mup + 4);
            float4 u2 = *(const float4*)(mup + 8);
            float4 u3 = *(const float4*)(mup + 12);
            mup += 16;
            FMA4(u0, 0) FMA4(u1, 4) FMA4(u2, 8) FMA4(u3, 12)
        }
    }
    #pragma unroll
    for (int d = 0; d < 8; ++d) {                   // peeled last group: no loads
        float2 wv = f[d];
        float4 u0 = *(const float4*)(mup);
        float4 u1 = *(const float4*)(mup + 4);
        float4 u2 = *(const float4*)(mup + 8);
        float4 u3 = *(const float4*)(mup + 12);
        mup += 16;
        FMA4(u0, 0) FMA4(u1, 4) FMA4(u2, 8) FMA4(u3, 12)
    }

    // 4-pass reduce over waves. Lane ln owns cols base+2ln (a0) / base+2ln+1 (a1).
    // Pass: stage 8 b's -> barrier -> thread (w,ln) sums b=BOFS+w, stores -> barrier.
#define REDPASS(ARR, BOFS, COLOFS) \
    { \
        _Pragma("unroll") \
        for (int i = 0; i < 8; ++i) red2[w][i][ln] = ARR[BOFS + i]; \
        __syncthreads(); \
        float s = 0.f; \
        _Pragma("unroll") \
        for (int ww = 0; ww < 8; ++ww) s += red2[ww][w][ln]; \
        int col = base + (ln << 1) + COLOFS; \
        outp[(size_t)(BOFS + w) * ncols + col] = s + bias[col]; \
        __syncthreads(); \
    }
    REDPASS(a0, 0, 0)
    REDPASS(a0, 8, 0)
    REDPASS(a1, 0, 1)
    REDPASS(a1, 8, 1)
#undef REDPASS
}

// ---------------------------------------------------------------------------
// k_red: finalize avg/max pooling (96 blocks); tile 0 also computes
// bs[b] = dot(mu[b], Bgs) + bbs.
__global__ __launch_bounds__(128) void k_red(
    const float* __restrict__ psum, const float* __restrict__ pmax,
    const float* __restrict__ mu, const float* __restrict__ Bgs,
    const float* __restrict__ bbs,
    float* __restrict__ avgb, float* __restrict__ maxb, float* __restrict__ bs)
{
    int b = blockIdx.x / 6, tile = blockIdx.x % 6, tid = threadIdx.x;
    int d = tile * 128 + tid;
    float s = 0.f, mx = -3.4e38f;
    for (int c = 0; c < 32; ++c) {
        size_t idx = ((size_t)(c * B_ + b)) * D_ + d;
        s += psum[idx];
        mx = fmaxf(mx, pmax[idx]);
    }
    avgb[b * D_ + d] = s * (1.f / 1024.f);
    maxb[b * D_ + d] = mx;

    if (tile == 0) {
        __shared__ float sb[128];
        float p = 0.f;
        for (int m = tid; m < MU_; m += 128) p += mu[b * MU_ + m] * Bgs[m];
        sb[tid] = p;
        __syncthreads();
        if (tid < 64) {
            float v = sb[tid] + sb[tid + 64];
            #pragma unroll
            for (int k = 32; k; k >>= 1) v += __shfl_xor(v, k, 64);
            if (tid == 0) bs[b] = v + bbs[0];
        }
    }
}

// ---------------------------------------------------------------------------
// k_c1: g[b][o] = relu(W1[b,o]@avg + b1) + relu(W1[b,o]@max + b1),
// b1 = dot(mu[b], Bg1[:,o]) + bb1[o] folded in. grid 768 x 64 (1 wave).
__global__ __launch_bounds__(64) void k_c1(
    const float* __restrict__ w1, const float* __restrict__ avgb,
    const float* __restrict__ maxb, const float* __restrict__ mu,
    const float* __restrict__ Bg1, const float* __restrict__ bb1,
    float* __restrict__ g)
{
    int b = blockIdx.x / 48, o = blockIdx.x % 48, ln = threadIdx.x;
    const float* row = w1 + (size_t)b * 36864 + o * 768;
    const float* av  = avgb + b * D_;
    const float* mxp = maxb + b * D_;
    const float* mub = mu + b * MU_;
    float pa = 0.f, pm = 0.f, pb = 0.f;
    #pragma unroll
    for (int i = 0; i < 12; ++i) {
        int idx = ln + (i << 6);
        float wv = row[idx];
        pa += wv * av[idx];
        pm += wv * mxp[idx];
        pb += Bg1[(size_t)idx * 48 + o] * mub[idx];
    }
    #pragma unroll
    for (int k = 32; k; k >>= 1) {
        pa += __shfl_xor(pa, k, 64);
        pm += __shfl_xor(pm, k, 64);
        pb += __shfl_xor(pb, k, 64);
    }
    if (ln == 0) {
        float bb = pb + bb1[o];
        g[b * 48 + o] = fmaxf(pa + bb, 0.f) + fmaxf(pm + bb, 0.f);
    }
}

// ---------------------------------------------------------------------------
// k_c2: att = W2[b,d,:]@g[b] + 2*b2[b,d]; cg = sigmoid(att). grid 192 x 64.
__global__ __launch_bounds__(64) void k_c2(
    const float* __restrict__ w2, const float* __restrict__ b2w,
    const float* __restrict__ g, float* __restrict__ cg)
{
    __shared__ float gL[48];
    int b = blockIdx.x / 12, tile = blockIdx.x % 12, ln = threadIdx.x;
    if (ln < 48) gL[ln] = g[b * 48 + ln];
    __syncthreads();
    int d = (tile << 6) + ln;
    const float* row = w2 + (size_t)b * 36864 + d * 48;
    float att = 0.f;
    #pragma unroll
    for (int o = 0; o < 48; o += 4) {
        float4 w4 = *(const float4*)(row + o);
        att += w4.x * gL[o] + w4.y * gL[o + 1] + w4.z * gL[o + 2] + w4.w * gL[o + 3];
    }
    att += 2.f * b2w[b * D_ + d];
    cg[b * D_ + d] = 1.f / (1.f + expf(-att));
}

// ---------------------------------------------------------------------------
// k_final: one wave per token: xg = x*cg; s = dot(xg, Ws)+bs; out = xg*sigmoid(s).
__global__ __launch_bounds__(256) void k_final(
    const float* __restrict__ x, const float* __restrict__ cg,
    const float* __restrict__ wsw, const float* __restrict__ bs,
    float* __restrict__ out)
{
    int wv = threadIdx.x >> 6, ln = threadIdx.x & 63;
    int tok = (blockIdx.x << 2) + wv;
    int b = tok >> 10;
    const float* xp = x + (size_t)tok * D_;
    const float* cp = cg + b * D_;
    const float* wp = wsw + b * D_;
    float xg[12];
    float part = 0.f;
    #pragma unroll
    for (int q = 0; q < 3; ++q) {
        int d = (q << 8) + (ln << 2);
        float4 xv = *(const float4*)(xp + d);
        float4 cv = *(const float4*)(cp + d);
        float4 w4 = *(const float4*)(wp + d);
        float g0 = xv.x * cv.x, g1 = xv.y * cv.y;
        float g2 = xv.z * cv.z, g3 = xv.w * cv.w;
        part += g0 * w4.x + g1 * w4.y + g2 * w4.z + g3 * w4.w;
        xg[q * 4 + 0] = g0; xg[q * 4 + 1] = g1;
        xg[q * 4 + 2] = g2; xg[q * 4 + 3] = g3;
    }
    #pragma unroll
    for (int k = 32; k; k >>= 1) part += __shfl_xor(part, k, 64);
    float s = part + bs[b];
    float sig = 1.f / (1.f + expf(-s));
    #pragma unroll
    for (int q = 0; q < 3; ++q) {
        int d = (q << 8) + (ln << 2);
        float4 o4 = { xg[q * 4 + 0] * sig, xg[q * 4 + 1] * sig,
                      xg[q * 4 + 2] * sig, xg[q * 4 + 3] * sig };
        *(float4*)(out + (size_t)tok * D_ + d) = o4;
    }
}

// ---------------------------------------------------------------------------
extern "C" void kernel_launch(void* const* d_in, const int* in_sizes, int n_in,
                              void* d_out, int out_size, void* d_ws, size_t ws_size,
                              hipStream_t stream)
{
    const float* x   = (const float*)d_in[0];
    const float* mu  = (const float*)d_in[1];
    const float* Wg1 = (const float*)d_in[2];
    const float* bg1 = (const float*)d_in[3];
    const float* Bg1 = (const float*)d_in[4];
    const float* bb1 = (const float*)d_in[5];
    const float* Wg2 = (const float*)d_in[6];
    const float* bg2 = (const float*)d_in[7];
    const float* Bg2 = (const float*)d_in[8];
    const float* bb2 = (const float*)d_in[9];
    const float* Wgs = (const float*)d_in[10];
    const float* bgs = (const float*)d_in[11];
    const float* Bgs = (const float*)d_in[12];
    const float* bbs = (const float*)d_in[13];
    float* base = (float*)d_ws;
    float* out  = (float*)d_out;

    float* mu_t = base;                  // 12288
    float* psum = mu_t + 12288;          // 393216
    float* pmax = psum + 393216;         // 393216
    float* w1   = pmax + 393216;         // 589824
    float* w2   = w1   + 589824;         // 589824
    float* wsw  = w2   + 589824;         // 12288
    float* b2   = wsw  + 12288;          // 12288
    float* avgb = b2   + 12288;          // 12288
    float* maxb = avgb + 12288;          // 12288
    float* g    = maxb + 12288;          // 768
    float* bs   = g    + 768;            // 16
    float* cg   = bs   + 16;             // 12288

    hipLaunchKernelGGL(k_pool,  dim3(513), dim3(192), 0, stream, x, mu, mu_t, psum, pmax);
    hipLaunchKernelGGL(k_hyper, dim3(588), dim3(512), 0, stream,
                       Wg1, bg1, Wg2, bg2, Wgs, bgs, Bg2, bb2,
                       mu_t, w1, w2, wsw, b2);
    hipLaunchKernelGGL(k_red,   dim3(96),  dim3(128), 0, stream,
                       psum, pmax, mu, Bgs, bbs, avgb, maxb, bs);
    hipLaunchKernelGGL(k_c1,    dim3(768), dim3(64),  0, stream,
                       w1, avgb, maxb, mu, Bg1, bb1, g);
    hipLaunchKernelGGL(k_c2,    dim3(192), dim3(64),  0, stream, w2, b2, g, cg);
    hipLaunchKernelGGL(k_final, dim3(4096), dim3(256), 0, stream, x, cg, wsw, bs, out);
}